// Round 7
// baseline (348.064 us; speedup 1.0000x reference)
//
#include <hip/hip_runtime.h>
#include <math.h>

typedef unsigned short u16;
typedef __attribute__((ext_vector_type(8))) short bf16x8;
typedef __attribute__((ext_vector_type(4))) float f32x4;

#define C_DIM 1024
#define N_TOK 2048

static __device__ __forceinline__ u16 f2bf(float f) {
  union { float f; unsigned u; } v; v.f = f;
  unsigned r = v.u + 0x7fff + ((v.u >> 16) & 1);
  return (u16)(r >> 16);
}

// ---------------- transpose + fp32->bf16 convert: W[K][N] -> WT[N][K] -----
__global__ __launch_bounds__(256) void convert_transpose(
    const float* __restrict__ W, u16* __restrict__ WT, int K, int N)
{
  __shared__ float tile[32][33];
  const int bx = blockIdx.x * 32;  // n
  const int by = blockIdx.y * 32;  // k
  const int tx = threadIdx.x & 31, ty = threadIdx.x >> 5;  // ty 0..7
  #pragma unroll
  for (int i = 0; i < 32; i += 8)
    tile[ty + i][tx] = W[(size_t)(by + ty + i) * N + bx + tx];
  __syncthreads();
  #pragma unroll
  for (int i = 0; i < 32; i += 8)
    WT[(size_t)(bx + ty + i) * K + by + tx] = f2bf(tile[tx][ty + i]);
}

// ---------------- LayerNorm: bf16 out (+ optional fp32 out) ---------------
__global__ __launch_bounds__(256) void ln_kernel(
    const float* __restrict__ x, const float* __restrict__ g,
    const float* __restrict__ b, u16* __restrict__ out,
    float* __restrict__ fout)
{
  const int row = blockIdx.x;
  const int t = threadIdx.x;
  const float* xr = x + (size_t)row * C_DIM;
  float4 xv = *(const float4*)(xr + t * 4);
  float s  = xv.x + xv.y + xv.z + xv.w;
  float ss = xv.x*xv.x + xv.y*xv.y + xv.z*xv.z + xv.w*xv.w;
  #pragma unroll
  for (int off = 1; off < 64; off <<= 1) {
    s  += __shfl_xor(s, off);
    ss += __shfl_xor(ss, off);
  }
  __shared__ float rs[4], rss[4];
  const int w = t >> 6;
  if ((t & 63) == 0) { rs[w] = s; rss[w] = ss; }
  __syncthreads();
  s  = rs[0] + rs[1] + rs[2] + rs[3];
  ss = rss[0] + rss[1] + rss[2] + rss[3];
  const float mean = s * (1.0f / C_DIM);
  const float var  = ss * (1.0f / C_DIM) - mean * mean;
  const float inv  = rsqrtf(var + 1e-5f);
  float4 gv = *(const float4*)(g + t * 4);
  float4 bv = *(const float4*)(b + t * 4);
  float4 o;
  o.x = (xv.x - mean) * inv * gv.x + bv.x;
  o.y = (xv.y - mean) * inv * gv.y + bv.y;
  o.z = (xv.z - mean) * inv * gv.z + bv.z;
  o.w = (xv.w - mean) * inv * gv.w + bv.w;
  ushort4 o4;
  o4.x = f2bf(o.x); o4.y = f2bf(o.y); o4.z = f2bf(o.z); o4.w = f2bf(o.w);
  *(ushort4*)(out + (size_t)row * C_DIM + t * 4) = o4;
  if (fout != nullptr)
    *(float4*)(fout + (size_t)row * C_DIM + t * 4) = o;
}

// ---------------- wbar[c][d] = mean over heads of k-weights ---------------
__global__ __launch_bounds__(256) void wbar_kernel(
    const float* __restrict__ qkv_w, float* __restrict__ wbar)
{
  const int idx = blockIdx.x * 256 + threadIdx.x;   // c*64 + d
  const int c = idx >> 6, d = idx & 63;
  float s = 0.f;
  #pragma unroll
  for (int h = 0; h < 16; h++)
    s += qkv_w[(size_t)c * 3072 + 1024 + h * 64 + d];
  wbar[idx] = s * (1.0f / 16.0f);
}

// ---------------- metric: 4 tokens/block, identical accumulation order ----
__global__ __launch_bounds__(256) void metric_gemm_kernel(
    const float* __restrict__ hf, const float* __restrict__ wbar,
    float* __restrict__ metric)
{
  __shared__ float hs[4][1024];
  const int n0 = blockIdx.x * 4;
  const int t = threadIdx.x;
  #pragma unroll
  for (int i = 0; i < 4; i++)
    *(float4*)&hs[i][t * 4] = *(const float4*)(hf + (size_t)(n0 + i) * 1024 + t * 4);
  __syncthreads();
  const int d = t & 63;
  const float* hsw = hs[t >> 6];
  float a0=0,a1=0,a2=0,a3=0,a4=0,a5=0,a6=0,a7=0;
  for (int c = 0; c < 1024; c += 8) {
    a0 += hsw[c+0] * wbar[(c+0)*64 + d];
    a1 += hsw[c+1] * wbar[(c+1)*64 + d];
    a2 += hsw[c+2] * wbar[(c+2)*64 + d];
    a3 += hsw[c+3] * wbar[(c+3)*64 + d];
    a4 += hsw[c+4] * wbar[(c+4)*64 + d];
    a5 += hsw[c+5] * wbar[(c+5)*64 + d];
    a6 += hsw[c+6] * wbar[(c+6)*64 + d];
    a7 += hsw[c+7] * wbar[(c+7)*64 + d];
  }
  float s = ((a0+a1)+(a2+a3)) + ((a4+a5)+(a6+a7));
  float sq = s * s;
  #pragma unroll
  for (int off = 1; off < 64; off <<= 1) sq += __shfl_xor(sq, off);
  metric[(size_t)(n0 + (t >> 6)) * 64 + d] = s / sqrtf(sq);
}

// ---------------- bf16 MFMA GEMM: C[M,N] = A[M,K] @ BT[N,K]^T -------------
template<int BM, int SPLIT, bool BIAS, bool GELU, bool RES, bool OUT_BF16>
__global__ __launch_bounds__(256) void gemm_mfma(
    const u16* __restrict__ A,   // [>=gridDim.y*BM][K] bf16 (readable padding)
    const u16* __restrict__ BT,  // [N][K] bf16
    const float* __restrict__ bias, const float* __restrict__ res,
    void* __restrict__ Cout, int M, int N, int K)
{
  constexpr int TM = BM / 32;                 // 16x16 tiles per wave (rows)
  __shared__ u16 As[BM * 64] __attribute__((aligned(16)));
  __shared__ u16 Bs[64 * 64] __attribute__((aligned(16)));
  const int tid  = threadIdx.x;
  const int lane = tid & 63;
  const int w    = tid >> 6;
  const int bm = blockIdx.y * BM;
  const int bn = blockIdx.x * 64;
  const int wm = (w >> 1) * (BM / 2);
  const int wn = (w & 1) * 32;

  f32x4 acc[TM][2] = {};

  const int rl = lane >> 3;                 // row-in-8-group
  const int cg = (lane & 7) ^ rl;           // swizzled source chunk

  const int kb = (K / SPLIT) * blockIdx.z;
  const int ke = kb + K / SPLIT;

  for (int k0 = kb; k0 < ke; k0 += 64) {
    #pragma unroll
    for (int i = 0; i < BM / 32; i++) {
      const int r = w * (BM / 4) + i * 8 + rl;
      __builtin_amdgcn_global_load_lds(
          (const __attribute__((address_space(1))) void*)(A + (size_t)(bm + r) * K + k0 + cg * 8),
          (__attribute__((address_space(3))) void*)(As + (w * (BM / 4) + i * 8) * 64),
          16, 0, 0);
    }
    #pragma unroll
    for (int i = 0; i < 2; i++) {
      const int r = w * 16 + i * 8 + rl;
      __builtin_amdgcn_global_load_lds(
          (const __attribute__((address_space(1))) void*)(BT + (size_t)(bn + r) * K + k0 + cg * 8),
          (__attribute__((address_space(3))) void*)(Bs + (w * 16 + i * 8) * 64),
          16, 0, 0);
    }
    __syncthreads();
    #pragma unroll
    for (int kk = 0; kk < 2; kk++) {
      bf16x8 af[TM], bfr[2];
      const int slot = (kk * 4 + (lane >> 4)) ^ (lane & 7);
      #pragma unroll
      for (int i = 0; i < TM; i++)
        af[i] = *(const bf16x8*)&As[(wm + i * 16 + (lane & 15)) * 64 + slot * 8];
      #pragma unroll
      for (int j = 0; j < 2; j++)
        bfr[j] = *(const bf16x8*)&Bs[(wn + j * 16 + (lane & 15)) * 64 + slot * 8];
      #pragma unroll
      for (int i = 0; i < TM; i++)
        #pragma unroll
        for (int j = 0; j < 2; j++)
          acc[i][j] = __builtin_amdgcn_mfma_f32_16x16x32_bf16(af[i], bfr[j], acc[i][j], 0, 0, 0);
    }
    __syncthreads();
  }

  if constexpr (SPLIT > 1) {
    float* Cf = (float*)Cout;
    #pragma unroll
    for (int i = 0; i < TM; i++)
      #pragma unroll
      for (int r = 0; r < 4; r++) {
        const int m = bm + wm + i * 16 + (lane >> 4) * 4 + r;
        if (m < M) {
          #pragma unroll
          for (int j = 0; j < 2; j++) {
            const int n = bn + wn + j * 16 + (lane & 15);
            atomicAdd(&Cf[(size_t)m * N + n], acc[i][j][r]);
          }
        }
      }
  } else {
    #pragma unroll
    for (int i = 0; i < TM; i++) {
      #pragma unroll
      for (int r = 0; r < 4; r++) {
        const int m = bm + wm + i * 16 + (lane >> 4) * 4 + r;
        if (m < M) {
          #pragma unroll
          for (int j = 0; j < 2; j++) {
            const int n = bn + wn + j * 16 + (lane & 15);
            float v = acc[i][j][r];
            if (BIAS) v += bias[n];
            if (GELU) v = 0.5f * v * (1.0f + erff(v * 0.70710678118654752f));
            if (RES)  v += res[(size_t)m * N + n];
            if (OUT_BF16) ((u16*)Cout)[(size_t)m * N + n] = f2bf(v);
            else          ((float*)Cout)[(size_t)m * N + n] = v;
          }
        }
      }
    }
  }
}

// ---------------- split-K epilogue: out = acc + bias + out (in-place res) -
__global__ __launch_bounds__(256) void splitk_epilogue_kernel(
    const float* __restrict__ acc, const float* __restrict__ bias,
    float* __restrict__ out, int M)
{
  const int idx = blockIdx.x * 256 + threadIdx.x;   // float4 index
  if (idx >= M * 256) return;
  float4 a = *(const float4*)(acc + idx * 4);
  float4 bv = *(const float4*)(bias + (idx & 255) * 4);
  float4 o = *(const float4*)(out + idx * 4);
  o.x += a.x + bv.x; o.y += a.y + bv.y; o.z += a.z + bv.z; o.w += a.w + bv.w;
  *(float4*)(out + idx * 4) = o;
}

// ---------------- V transpose: qkv v-part -> vt[h][d][token] (bf16) -------
__global__ __launch_bounds__(256) void vt_kernel(
    const u16* __restrict__ qkv, u16* __restrict__ vt)
{
  const int h  = blockIdx.y;
  const int t0 = blockIdx.x * 64;
  const int tid = threadIdx.x;
  __shared__ u16 tile[64][72];
  const int row = tid >> 3;   // 0..31
  const int ch  = tid & 7;
  #pragma unroll
  for (int i = 0; i < 2; i++) {
    const int tok = row + i * 32;
    *(bf16x8*)&tile[tok][ch * 8] =
        *(const bf16x8*)(qkv + (size_t)(t0 + tok) * 3072 + 2048 + h * 64 + ch * 8);
  }
  __syncthreads();
  #pragma unroll
  for (int i = 0; i < 2; i++) {
    const int d = row + i * 32;
    u16 tmp[8];
    #pragma unroll
    for (int j = 0; j < 8; j++) tmp[j] = tile[ch * 8 + j][d];
    *(bf16x8*)(vt + (size_t)(h * 64 + d) * 2048 + t0 + ch * 8) = *(bf16x8*)tmp;
  }
}

// ---------------- MFMA flash attention, no-max softmax ---------------------
// Block: 128 q-rows x 1 head; 4 waves x 32 q-rows (2 row-tiles each) so K/V
// LDS fragments are read once and feed 2 MFMAs. Key-split over blockIdx.z;
// partials combine by fp32 atomicAdd (exact sum, |score|<<80 so no max
// subtraction needed — softmax shift-invariance).
template<int SPLIT>
__global__ __launch_bounds__(256) void attn_mfma(
    const u16* __restrict__ qkv, const u16* __restrict__ vt,
    const float* __restrict__ sz, float* __restrict__ opart,
    float* __restrict__ lpart)
{
  const int h   = blockIdx.y;
  const int q0  = blockIdx.x * 128;
  const int tid = threadIdx.x;
  const int lane = tid & 63;
  const int w    = tid >> 6;
  const int col  = lane & 15;
  const int quad = lane >> 4;

  __shared__ u16 Ks [64 * 64] __attribute__((aligned(16)));
  __shared__ u16 Vts[64 * 64] __attribute__((aligned(16)));
  __shared__ u16 Ps[4][32 * 72] __attribute__((aligned(16)));  // per-wave P bf16
  __shared__ float lb[64];

  bf16x8 qf[2][2];
  #pragma unroll
  for (int rt = 0; rt < 2; rt++) {
    const u16* qp = qkv + (size_t)(q0 + w * 32 + rt * 16 + col) * 3072 + h * 64 + quad * 8;
    qf[rt][0] = *(const bf16x8*)(qp);
    qf[rt][1] = *(const bf16x8*)(qp + 32);
  }

  float l_part[2][4] = {};
  f32x4 oacc[2][4] = {};

  const int rl = lane >> 3;
  const int cg = (lane & 7) ^ rl;
  const int kb = blockIdx.z * (N_TOK / SPLIT);

  for (int kt = kb; kt < kb + N_TOK / SPLIT; kt += 64) {
    #pragma unroll
    for (int i = 0; i < 2; i++) {
      const int r = w * 16 + i * 8 + rl;
      __builtin_amdgcn_global_load_lds(
          (const __attribute__((address_space(1))) void*)(qkv + (size_t)(kt + r) * 3072 + 1024 + h * 64 + cg * 8),
          (__attribute__((address_space(3))) void*)(Ks + (w * 16 + i * 8) * 64),
          16, 0, 0);
      __builtin_amdgcn_global_load_lds(
          (const __attribute__((address_space(1))) void*)(vt + (size_t)(h * 64 + r) * 2048 + kt + cg * 8),
          (__attribute__((address_space(3))) void*)(Vts + (w * 16 + i * 8) * 64),
          16, 0, 0);
    }
    if (tid < 64) lb[tid] = __logf(sz[kt + tid]);
    __syncthreads();

    // S = Q K^T — K fragment read once, used by both row-tiles
    f32x4 sacc[2][4] = {};
    #pragma unroll
    for (int kk = 0; kk < 2; kk++) {
      const int slot = (kk * 4 + quad) ^ (lane & 7);
      #pragma unroll
      for (int jt = 0; jt < 4; jt++) {
        bf16x8 kf = *(const bf16x8*)&Ks[(jt * 16 + col) * 64 + slot * 8];
        #pragma unroll
        for (int rt = 0; rt < 2; rt++)
          sacc[rt][jt] = __builtin_amdgcn_mfma_f32_16x16x32_bf16(qf[rt][kk], kf, sacc[rt][jt], 0, 0, 0);
      }
    }

    float lbj[4];
    #pragma unroll
    for (int jt = 0; jt < 4; jt++) lbj[jt] = lb[jt * 16 + col];

    u16* pw = Ps[w];
    #pragma unroll
    for (int rt = 0; rt < 2; rt++) {
      #pragma unroll
      for (int r = 0; r < 4; r++) {
        const float p0 = __expf(fmaf(sacc[rt][0][r], 0.125f, lbj[0]));
        const float p1 = __expf(fmaf(sacc[rt][1][r], 0.125f, lbj[1]));
        const float p2 = __expf(fmaf(sacc[rt][2][r], 0.125f, lbj[2]));
        const float p3 = __expf(fmaf(sacc[rt][3][r], 0.125f, lbj[3]));
        l_part[rt][r] += (p0 + p1) + (p2 + p3);
        const int row = rt * 16 + quad * 4 + r;
        pw[row * 72 +  0 + col] = f2bf(p0);
        pw[row * 72 + 16 + col] = f2bf(p1);
        pw[row * 72 + 32 + col] = f2bf(p2);
        pw[row * 72 + 48 + col] = f2bf(p3);
      }
    }
    // same-wave LDS RAW -> lgkmcnt; stride 72 u16 keeps b128 reads aligned
    bf16x8 pf[2][2];
    #pragma unroll
    for (int rt = 0; rt < 2; rt++)
      #pragma unroll
      for (int kk = 0; kk < 2; kk++)
        pf[rt][kk] = *(const bf16x8*)&pw[(rt * 16 + col) * 72 + kk * 32 + quad * 8];

    // O += P V — V fragment read once, used by both row-tiles
    #pragma unroll
    for (int kk = 0; kk < 2; kk++) {
      const int slot = (kk * 4 + quad) ^ (lane & 7);
      #pragma unroll
      for (int nt = 0; nt < 4; nt++) {
        bf16x8 vf = *(const bf16x8*)&Vts[(nt * 16 + col) * 64 + slot * 8];
        #pragma unroll
        for (int rt = 0; rt < 2; rt++)
          oacc[rt][nt] = __builtin_amdgcn_mfma_f32_16x16x32_bf16(pf[rt][kk], vf, oacc[rt][nt], 0, 0, 0);
      }
    }
    __syncthreads();
  }

  // reduce l across the 16-lane col group (once, at the end)
  #pragma unroll
  for (int rt = 0; rt < 2; rt++)
    #pragma unroll
    for (int r = 0; r < 4; r++) {
      float l = l_part[rt][r];
      l += __shfl_xor(l, 1); l += __shfl_xor(l, 2);
      l += __shfl_xor(l, 4); l += __shfl_xor(l, 8);
      l_part[rt][r] = l;
    }

  #pragma unroll
  for (int rt = 0; rt < 2; rt++)
    #pragma unroll
    for (int r = 0; r < 4; r++) {
      const int q = q0 + w * 32 + rt * 16 + quad * 4 + r;
      float* op = opart + (size_t)q * 1024 + h * 64 + col;
      #pragma unroll
      for (int nt = 0; nt < 4; nt++)
        atomicAdd(op + nt * 16, oacc[rt][nt][r]);
      if (col == 0) atomicAdd(&lpart[q * 16 + h], l_part[rt][r]);
    }
}

// ---------------- normalize O by l, emit bf16 xa --------------------------
__global__ __launch_bounds__(256) void attn_norm_kernel(
    const float* __restrict__ opart, const float* __restrict__ lpart,
    u16* __restrict__ xa)
{
  const int q = blockIdx.x;
  const int c = threadIdx.x * 4;
  float4 o = *(const float4*)(opart + (size_t)q * 1024 + c);
  const float inv = 1.0f / lpart[q * 16 + (c >> 6)];
  ushort4 o4;
  o4.x = f2bf(o.x * inv); o4.y = f2bf(o.y * inv);
  o4.z = f2bf(o.z * inv); o4.w = f2bf(o.w * inv);
  *(ushort4*)(xa + (size_t)q * 1024 + c) = o4;
}

// ---------------- merge scores: 4 src/block, identical comparator ---------
__global__ __launch_bounds__(256) void merge_score_kernel(
    const float* __restrict__ metric, const float* __restrict__ thr,
    int* __restrict__ mask, int* __restrict__ node)
{
  const int s0 = blockIdx.x * 4;
  const int t = threadIdx.x;
  __shared__ float a[4][64];
  a[t >> 6][t & 63] = metric[(size_t)(2 * (s0 + (t >> 6))) * 64 + (t & 63)];
  __syncthreads();
  float best[4] = {-INFINITY, -INFINITY, -INFINITY, -INFINITY};
  int besti[4] = {0, 0, 0, 0};
  for (int m = t; m < 1024; m += 256) {
    const float* bp = metric + (size_t)(2 * m + 1) * 64;
    float s[4] = {0.f, 0.f, 0.f, 0.f};
    #pragma unroll
    for (int d = 0; d < 64; d += 4) {
      float4 bv = *(const float4*)(bp + d);
      #pragma unroll
      for (int j = 0; j < 4; j++) {
        float4 av = *(const float4*)&a[j][d];
        s[j] += av.x*bv.x + av.y*bv.y + av.z*bv.z + av.w*bv.w;
      }
    }
    #pragma unroll
    for (int j = 0; j < 4; j++)
      if (s[j] > best[j]) { best[j] = s[j]; besti[j] = m; }   // ascending m
  }
  #pragma unroll
  for (int j = 0; j < 4; j++) {
    float b = best[j]; int bi = besti[j];
    #pragma unroll
    for (int off = 1; off < 64; off <<= 1) {
      float ov = __shfl_xor(b, off);
      int   oi = __shfl_xor(bi, off);
      if (ov > b || (ov == b && oi < bi)) { b = ov; bi = oi; }
    }
    best[j] = b; besti[j] = bi;
  }
  __shared__ float bw_[4][4]; __shared__ int biw_[4][4];
  const int wv = t >> 6;
  if ((t & 63) == 0) {
    #pragma unroll
    for (int j = 0; j < 4; j++) { bw_[wv][j] = best[j]; biw_[wv][j] = besti[j]; }
  }
  __syncthreads();
  if (t < 4) {
    const int j = t;
    float b = bw_[0][j]; int bi = biw_[0][j];
    for (int ww = 1; ww < 4; ww++)
      if (bw_[ww][j] > b || (bw_[ww][j] == b && biw_[ww][j] < bi)) { b = bw_[ww][j]; bi = biw_[ww][j]; }
    const int n = s0 + j;
    if (n == 0) { mask[0] = 0; node[0] = 0; }
    else { mask[n] = (b > thr[0]) ? 1 : 0; node[n] = bi; }
  }
}

// ---------------- exclusive prefix-sum of !mask (1024 entries) ------------
__global__ __launch_bounds__(1024) void scan_kernel(
    const int* __restrict__ mask, int* __restrict__ pos)
{
  __shared__ int s[1024];
  const int t = threadIdx.x;
  const int v0 = mask[t] ? 0 : 1;
  s[t] = v0;
  __syncthreads();
  for (int off = 1; off < 1024; off <<= 1) {
    int v = (t >= off) ? s[t - off] : 0;
    __syncthreads();
    s[t] += v;
    __syncthreads();
  }
  pos[t] = s[t] - v0;
}

// ---------------- build merged rows (unm gather + dst base) ---------------
__global__ __launch_bounds__(256) void build_kernel(
    const float* __restrict__ xres, const float* __restrict__ sz,
    const int* __restrict__ mask, const int* __restrict__ pos,
    float* __restrict__ xm, float* __restrict__ sizem, int U)
{
  const int b = blockIdx.x;
  const int t = threadIdx.x;
  int srow, orow;
  if (b < 1024) { srow = 2 * b + 1; orow = U + b; }
  else {
    const int i = b - 1024;
    if (mask[i]) return;
    srow = 2 * i; orow = pos[i];
  }
  const float ssz = sz[srow];
  const float* xp = xres + (size_t)srow * 1024;
  float* op = xm + (size_t)orow * 1024;
  const int c = t * 4;
  float4 v = *(const float4*)(xp + c);
  v.x *= ssz; v.y *= ssz; v.z *= ssz; v.w *= ssz;
  *(float4*)(op + c) = v;
  if (t == 0) sizem[orow] = ssz;
}

// ---------------- scatter-add merged src tokens into dst rows -------------
__global__ __launch_bounds__(256) void merge_add_kernel(
    const float* __restrict__ xres, const float* __restrict__ sz,
    const int* __restrict__ mask, const int* __restrict__ node,
    float* __restrict__ xm, float* __restrict__ sizem, int U)
{
  const int i = blockIdx.x;
  if (!mask[i]) return;
  const int t = threadIdx.x;
  const int srow = 2 * i;
  const int orow = U + node[i];
  const float ssz = sz[srow];
  const float* xp = xres + (size_t)srow * 1024;
  float* op = xm + (size_t)orow * 1024;
  for (int c = t; c < 1024; c += 256)
    atomicAdd(op + c, xp[c] * ssz);
  if (t == 0) atomicAdd(sizem + orow, ssz);
}

// ---------------- divide by size; emit x and size outputs -----------------
__global__ __launch_bounds__(256) void divide_kernel(
    const float* __restrict__ xm, const float* __restrict__ sizem,
    float* __restrict__ outx, float* __restrict__ outs, int M)
{
  const int total = M * 1024;
  for (int idx = blockIdx.x * 256 + threadIdx.x; idx < total; idx += gridDim.x * 256)
    outx[idx] = xm[idx] / sizem[idx >> 10];
  const int idx2 = blockIdx.x * 256 + threadIdx.x;
  if (idx2 < M) outs[idx2] = sizem[idx2];
}

extern "C" void kernel_launch(void* const* d_in, const int* in_sizes, int n_in,
                              void* d_out, int out_size, void* d_ws, size_t ws_size,
                              hipStream_t stream) {
  const float* x      = (const float*)d_in[0];
  const float* sz     = (const float*)d_in[1];
  const float* qkv_w  = (const float*)d_in[2];
  const float* proj_w = (const float*)d_in[3];
  const float* proj_b = (const float*)d_in[4];
  const float* ln1_g  = (const float*)d_in[5];
  const float* ln1_b  = (const float*)d_in[6];
  const float* ln2_g  = (const float*)d_in[7];
  const float* ln2_b  = (const float*)d_in[8];
  const float* fc1_w  = (const float*)d_in[9];
  const float* fc1_b  = (const float*)d_in[10];
  const float* fc2_w  = (const float*)d_in[11];
  const float* fc2_b  = (const float*)d_in[12];
  const float* thr    = (const float*)d_in[13];

  const int M = out_size / 1025;
  const int U = M - 1024;
  const size_t MB = 1u << 20;
  const size_t KB = 1u << 10;

  // workspace overlays (lifetimes sequential on `stream`):
  //  early: w_qkvT[0,6) -> b_vt[0,4); wbar/met/mask@[6,7); lpart@[7,7.13);
  //         w_projT[8,10); b_qkv[10,22) -> b_xm[10,18);
  //         b_hf[22,30) -> opart[22,30) -> b_xres[22,30);
  //         b_h[30,34) -> b_xa[30,34)
  //  late:  w_fc1T[0,8); b_g[8,21); w_fc2T[21,29); facc[29,35); b_h2[35,39)
  char* ws = (char*)d_ws;
  u16*   w_qkvT  = (u16*)(ws + 0);
  float* b_wbar  = (float*)(ws + 6 * MB);
  float* b_met   = (float*)(ws + 6 * MB + 256 * KB);
  int*   b_mask  = (int*)(ws + 6 * MB + 768 * KB);
  int*   b_node  = b_mask + 1024;
  int*   b_pos   = b_node + 1024;
  float* b_szm   = (float*)(b_pos + 1024);
  float* b_lpart = (float*)(ws + 7 * MB);
  u16*   w_projT = (u16*)(ws + 8 * MB);
  u16*   b_qkv   = (u16*)(ws + 10 * MB);
  float* b_xm    = (float*)(ws + 10 * MB);   // over dead b_qkv
  float* b_hf    = (float*)(ws + 22 * MB);
  float* b_opart = (float*)(ws + 22 * MB);   // over dead b_hf
  float* b_xres  = (float*)(ws + 22 * MB);   // over dead opart
  u16*   b_h     = (u16*)(ws + 30 * MB);
  u16*   b_xa    = (u16*)(ws + 30 * MB);
  u16*   b_vt    = (u16*)(ws + 0);
  u16*   w_fc1T  = (u16*)(ws + 0);
  u16*   b_g     = (u16*)(ws + 8 * MB);
  u16*   w_fc2T  = (u16*)(ws + 21 * MB);
  float* b_facc  = (float*)(ws + 29 * MB);
  u16*   b_h2    = (u16*)(ws + 35 * MB);

  float* outx = (float*)d_out;
  float* outs = outx + (size_t)M * 1024;

  // 1. LN1 -> bf16 (for MFMA) + fp32 (for exact metric path)
  ln_kernel<<<2048, 256, 0, stream>>>(x, ln1_g, ln1_b, b_h, b_hf);
  // 2. mean-over-heads k-weights (fp32)
  wbar_kernel<<<256, 256, 0, stream>>>(qkv_w, b_wbar);
  // 3. weight converts for attention half
  convert_transpose<<<dim3(96, 32), 256, 0, stream>>>(qkv_w, w_qkvT, 1024, 3072);
  convert_transpose<<<dim3(32, 32), 256, 0, stream>>>(proj_w, w_projT, 1024, 1024);
  // 4. QKV GEMM (bf16 MFMA), bf16 out — 768 blocks
  gemm_mfma<128, 1, false, false, false, true><<<dim3(48, 16), 256, 0, stream>>>(
      b_h, w_qkvT, nullptr, nullptr, b_qkv, 2048, 3072, 1024);
  // 4b. V transpose for MFMA attention (overwrites dead w_qkvT)
  vt_kernel<<<dim3(32, 16), 256, 0, stream>>>(b_qkv, b_vt);
  // 5. exact fp32 metric (decoupled from bf16 path — merge decisions stable)
  metric_gemm_kernel<<<512, 256, 0, stream>>>(b_hf, b_wbar, b_met);
  // 6. MFMA attention, 128q/block, key-split=4, atomic fp32 partials
  hipMemsetAsync(b_opart, 0, 8 * MB, stream);
  hipMemsetAsync(b_lpart, 0, 128 * KB, stream);
  attn_mfma<4><<<dim3(16, 16, 4), 256, 0, stream>>>(b_qkv, b_vt, sz, b_opart, b_lpart);
  attn_norm_kernel<<<2048, 256, 0, stream>>>(b_opart, b_lpart, b_xa);
  // 7. proj GEMM + bias + residual(x) -> xres fp32 — 512 blocks
  gemm_mfma<64, 1, true, false, true, false><<<dim3(16, 32), 256, 0, stream>>>(
      b_xa, w_projT, proj_b, x, b_xres, 2048, 1024, 1024);
  // 8-11. merge pipeline
  merge_score_kernel<<<256, 256, 0, stream>>>(b_met, thr, b_mask, b_node);
  scan_kernel<<<1, 1024, 0, stream>>>(b_mask, b_pos);
  build_kernel<<<2048, 256, 0, stream>>>(b_xres, sz, b_mask, b_pos, b_xm, b_szm, U);
  merge_add_kernel<<<1024, 256, 0, stream>>>(b_xres, sz, b_mask, b_node, b_xm, b_szm, U);
  // 12. divide + emit outputs
  divide_kernel<<<2048, 256, 0, stream>>>(b_xm, b_szm, outx, outs, M);
  // 13. late weight converts (into now-dead regions)
  convert_transpose<<<dim3(128, 32), 256, 0, stream>>>(fc1_w, w_fc1T, 1024, 4096);
  convert_transpose<<<dim3(32, 128), 256, 0, stream>>>(fc2_w, w_fc2T, 4096, 1024);
  // 14. LN2 -> bf16
  ln_kernel<<<M, 256, 0, stream>>>(outx, ln2_g, ln2_b, b_h2, nullptr);
  // 15. fc1 + bias + exact GELU -> bf16 — 768 blocks
  gemm_mfma<128, 1, true, true, false, true><<<dim3(64, (M + 127) / 128), 256, 0, stream>>>(
      b_h2, w_fc1T, fc1_b, nullptr, b_g, M, 4096, 1024);
  // 16. fc2 split-K=4 -> fp32 atomic accumulator
  hipMemsetAsync(b_facc, 0, (size_t)M * 1024 * 4, stream);
  gemm_mfma<64, 4, false, false, false, false><<<dim3(16, (M + 63) / 64, 4), 256, 0, stream>>>(
      b_g, w_fc2T, nullptr, nullptr, b_facc, M, 1024, 4096);
  // 17. fc2 epilogue: outx += facc + bias (residual in-place)
  splitk_epilogue_kernel<<<(M * 256 + 255) / 256, 256, 0, stream>>>(
      b_facc, fc2_b, outx, M);
  (void)in_sizes; (void)n_in; (void)ws_size;
}

// Round 9
// 331.596 us; speedup vs baseline: 1.0497x; 1.0497x over previous
//
#include <hip/hip_runtime.h>
#include <math.h>

typedef unsigned short u16;
typedef __attribute__((ext_vector_type(8))) short bf16x8;
typedef __attribute__((ext_vector_type(4))) float f32x4;

#define C_DIM 1024
#define N_TOK 2048

static __device__ __forceinline__ u16 f2bf(float f) {
  union { float f; unsigned u; } v; v.f = f;
  unsigned r = v.u + 0x7fff + ((v.u >> 16) & 1);
  return (u16)(r >> 16);
}

// ---------------- transpose + fp32->bf16 convert: W[K][N] -> WT[N][K] -----
__global__ __launch_bounds__(256) void convert_transpose(
    const float* __restrict__ W, u16* __restrict__ WT, int K, int N)
{
  __shared__ float tile[32][33];
  const int bx = blockIdx.x * 32;  // n
  const int by = blockIdx.y * 32;  // k
  const int tx = threadIdx.x & 31, ty = threadIdx.x >> 5;  // ty 0..7
  #pragma unroll
  for (int i = 0; i < 32; i += 8)
    tile[ty + i][tx] = W[(size_t)(by + ty + i) * N + bx + tx];
  __syncthreads();
  #pragma unroll
  for (int i = 0; i < 32; i += 8)
    WT[(size_t)(bx + ty + i) * K + by + tx] = f2bf(tile[tx][ty + i]);
}

// ---------------- LayerNorm: bf16 out (+ optional fp32 out) ---------------
__global__ __launch_bounds__(256) void ln_kernel(
    const float* __restrict__ x, const float* __restrict__ g,
    const float* __restrict__ b, u16* __restrict__ out,
    float* __restrict__ fout)
{
  const int row = blockIdx.x;
  const int t = threadIdx.x;
  const float* xr = x + (size_t)row * C_DIM;
  float4 xv = *(const float4*)(xr + t * 4);
  float s  = xv.x + xv.y + xv.z + xv.w;
  float ss = xv.x*xv.x + xv.y*xv.y + xv.z*xv.z + xv.w*xv.w;
  #pragma unroll
  for (int off = 1; off < 64; off <<= 1) {
    s  += __shfl_xor(s, off);
    ss += __shfl_xor(ss, off);
  }
  __shared__ float rs[4], rss[4];
  const int w = t >> 6;
  if ((t & 63) == 0) { rs[w] = s; rss[w] = ss; }
  __syncthreads();
  s  = rs[0] + rs[1] + rs[2] + rs[3];
  ss = rss[0] + rss[1] + rss[2] + rss[3];
  const float mean = s * (1.0f / C_DIM);
  const float var  = ss * (1.0f / C_DIM) - mean * mean;
  const float inv  = rsqrtf(var + 1e-5f);
  float4 gv = *(const float4*)(g + t * 4);
  float4 bv = *(const float4*)(b + t * 4);
  float4 o;
  o.x = (xv.x - mean) * inv * gv.x + bv.x;
  o.y = (xv.y - mean) * inv * gv.y + bv.y;
  o.z = (xv.z - mean) * inv * gv.z + bv.z;
  o.w = (xv.w - mean) * inv * gv.w + bv.w;
  ushort4 o4;
  o4.x = f2bf(o.x); o4.y = f2bf(o.y); o4.z = f2bf(o.z); o4.w = f2bf(o.w);
  *(ushort4*)(out + (size_t)row * C_DIM + t * 4) = o4;
  if (fout != nullptr)
    *(float4*)(fout + (size_t)row * C_DIM + t * 4) = o;
}

// ---------------- wbar[c][d] = mean over heads of k-weights ---------------
__global__ __launch_bounds__(256) void wbar_kernel(
    const float* __restrict__ qkv_w, float* __restrict__ wbar)
{
  const int idx = blockIdx.x * 256 + threadIdx.x;   // c*64 + d
  const int c = idx >> 6, d = idx & 63;
  float s = 0.f;
  #pragma unroll
  for (int h = 0; h < 16; h++)
    s += qkv_w[(size_t)c * 3072 + 1024 + h * 64 + d];
  wbar[idx] = s * (1.0f / 16.0f);
}

// ---------------- metric: 4 tokens/block, identical accumulation order ----
__global__ __launch_bounds__(256) void metric_gemm_kernel(
    const float* __restrict__ hf, const float* __restrict__ wbar,
    float* __restrict__ metric)
{
  __shared__ float hs[4][1024];
  const int n0 = blockIdx.x * 4;
  const int t = threadIdx.x;
  #pragma unroll
  for (int i = 0; i < 4; i++)
    *(float4*)&hs[i][t * 4] = *(const float4*)(hf + (size_t)(n0 + i) * 1024 + t * 4);
  __syncthreads();
  const int d = t & 63;
  const float* hsw = hs[t >> 6];
  float a0=0,a1=0,a2=0,a3=0,a4=0,a5=0,a6=0,a7=0;
  for (int c = 0; c < 1024; c += 8) {
    a0 += hsw[c+0] * wbar[(c+0)*64 + d];
    a1 += hsw[c+1] * wbar[(c+1)*64 + d];
    a2 += hsw[c+2] * wbar[(c+2)*64 + d];
    a3 += hsw[c+3] * wbar[(c+3)*64 + d];
    a4 += hsw[c+4] * wbar[(c+4)*64 + d];
    a5 += hsw[c+5] * wbar[(c+5)*64 + d];
    a6 += hsw[c+6] * wbar[(c+6)*64 + d];
    a7 += hsw[c+7] * wbar[(c+7)*64 + d];
  }
  float s = ((a0+a1)+(a2+a3)) + ((a4+a5)+(a6+a7));
  float sq = s * s;
  #pragma unroll
  for (int off = 1; off < 64; off <<= 1) sq += __shfl_xor(sq, off);
  metric[(size_t)(n0 + (t >> 6)) * 64 + d] = s / sqrtf(sq);
}

// ---------------- bf16 MFMA GEMM: C[M,N] = A[M,K] @ BT[N,K]^T -------------
template<int BM, int SPLIT, bool BIAS, bool GELU, bool RES, bool OUT_BF16>
__global__ __launch_bounds__(256) void gemm_mfma(
    const u16* __restrict__ A,   // [>=gridDim.y*BM][K] bf16 (readable padding)
    const u16* __restrict__ BT,  // [N][K] bf16
    const float* __restrict__ bias, const float* __restrict__ res,
    void* __restrict__ Cout, int M, int N, int K)
{
  constexpr int TM = BM / 32;                 // 16x16 tiles per wave (rows)
  __shared__ u16 As[BM * 64] __attribute__((aligned(16)));
  __shared__ u16 Bs[64 * 64] __attribute__((aligned(16)));
  const int tid  = threadIdx.x;
  const int lane = tid & 63;
  const int w    = tid >> 6;
  const int bm = blockIdx.y * BM;
  const int bn = blockIdx.x * 64;
  const int wm = (w >> 1) * (BM / 2);
  const int wn = (w & 1) * 32;

  f32x4 acc[TM][2] = {};

  const int rl = lane >> 3;                 // row-in-8-group
  const int cg = (lane & 7) ^ rl;           // swizzled source chunk

  const int kb = (K / SPLIT) * blockIdx.z;
  const int ke = kb + K / SPLIT;

  for (int k0 = kb; k0 < ke; k0 += 64) {
    #pragma unroll
    for (int i = 0; i < BM / 32; i++) {
      const int r = w * (BM / 4) + i * 8 + rl;
      __builtin_amdgcn_global_load_lds(
          (const __attribute__((address_space(1))) void*)(A + (size_t)(bm + r) * K + k0 + cg * 8),
          (__attribute__((address_space(3))) void*)(As + (w * (BM / 4) + i * 8) * 64),
          16, 0, 0);
    }
    #pragma unroll
    for (int i = 0; i < 2; i++) {
      const int r = w * 16 + i * 8 + rl;
      __builtin_amdgcn_global_load_lds(
          (const __attribute__((address_space(1))) void*)(BT + (size_t)(bn + r) * K + k0 + cg * 8),
          (__attribute__((address_space(3))) void*)(Bs + (w * 16 + i * 8) * 64),
          16, 0, 0);
    }
    __syncthreads();
    #pragma unroll
    for (int kk = 0; kk < 2; kk++) {
      bf16x8 af[TM], bfr[2];
      const int slot = (kk * 4 + (lane >> 4)) ^ (lane & 7);
      #pragma unroll
      for (int i = 0; i < TM; i++)
        af[i] = *(const bf16x8*)&As[(wm + i * 16 + (lane & 15)) * 64 + slot * 8];
      #pragma unroll
      for (int j = 0; j < 2; j++)
        bfr[j] = *(const bf16x8*)&Bs[(wn + j * 16 + (lane & 15)) * 64 + slot * 8];
      #pragma unroll
      for (int i = 0; i < TM; i++)
        #pragma unroll
        for (int j = 0; j < 2; j++)
          acc[i][j] = __builtin_amdgcn_mfma_f32_16x16x32_bf16(af[i], bfr[j], acc[i][j], 0, 0, 0);
    }
    __syncthreads();
  }

  if constexpr (SPLIT > 1) {
    float* Cf = (float*)Cout;
    #pragma unroll
    for (int i = 0; i < TM; i++)
      #pragma unroll
      for (int r = 0; r < 4; r++) {
        const int m = bm + wm + i * 16 + (lane >> 4) * 4 + r;
        if (m < M) {
          #pragma unroll
          for (int j = 0; j < 2; j++) {
            const int n = bn + wn + j * 16 + (lane & 15);
            atomicAdd(&Cf[(size_t)m * N + n], acc[i][j][r]);
          }
        }
      }
  } else {
    #pragma unroll
    for (int i = 0; i < TM; i++) {
      #pragma unroll
      for (int r = 0; r < 4; r++) {
        const int m = bm + wm + i * 16 + (lane >> 4) * 4 + r;
        if (m < M) {
          #pragma unroll
          for (int j = 0; j < 2; j++) {
            const int n = bn + wn + j * 16 + (lane & 15);
            float v = acc[i][j][r];
            if (BIAS) v += bias[n];
            if (GELU) v = 0.5f * v * (1.0f + erff(v * 0.70710678118654752f));
            if (RES)  v += res[(size_t)m * N + n];
            if (OUT_BF16) ((u16*)Cout)[(size_t)m * N + n] = f2bf(v);
            else          ((float*)Cout)[(size_t)m * N + n] = v;
          }
        }
      }
    }
  }
}

// ---------------- split-K epilogue: out = acc + bias + out (in-place res) -
__global__ __launch_bounds__(256) void splitk_epilogue_kernel(
    const float* __restrict__ acc, const float* __restrict__ bias,
    float* __restrict__ out, int M)
{
  const int idx = blockIdx.x * 256 + threadIdx.x;   // float4 index
  if (idx >= M * 256) return;
  float4 a = *(const float4*)(acc + idx * 4);
  float4 bv = *(const float4*)(bias + (idx & 255) * 4);
  float4 o = *(const float4*)(out + idx * 4);
  o.x += a.x + bv.x; o.y += a.y + bv.y; o.z += a.z + bv.z; o.w += a.w + bv.w;
  *(float4*)(out + idx * 4) = o;
}

// ---------------- V transpose: qkv v-part -> vt[h][d][token] (bf16) -------
__global__ __launch_bounds__(256) void vt_kernel(
    const u16* __restrict__ qkv, u16* __restrict__ vt)
{
  const int h  = blockIdx.y;
  const int t0 = blockIdx.x * 64;
  const int tid = threadIdx.x;
  __shared__ u16 tile[64][72];
  const int row = tid >> 3;   // 0..31
  const int ch  = tid & 7;
  #pragma unroll
  for (int i = 0; i < 2; i++) {
    const int tok = row + i * 32;
    *(bf16x8*)&tile[tok][ch * 8] =
        *(const bf16x8*)(qkv + (size_t)(t0 + tok) * 3072 + 2048 + h * 64 + ch * 8);
  }
  __syncthreads();
  #pragma unroll
  for (int i = 0; i < 2; i++) {
    const int d = row + i * 32;
    u16 tmp[8];
    #pragma unroll
    for (int j = 0; j < 8; j++) tmp[j] = tile[ch * 8 + j][d];
    *(bf16x8*)(vt + (size_t)(h * 64 + d) * 2048 + t0 + ch * 8) = *(bf16x8*)tmp;
  }
}

// ---------------- MFMA flash attention, no-max softmax, S^T trick ---------
// R6 shape (64 q-rows/block, 4 waves, split=2) + S^T = K Q^T so each lane's
// C-layout P values are 4 CONSECUTIVE keys of ONE q-column:
//   -> P-writes: 4x ds_write_b64 (was 16x ds_write_b16)
//   -> l: one scalar accumulator/lane, reduced once at the end (2 shuffles)
// Scores = qk/8 + log(size), |s| << 80 -> exp safe without max subtraction.
template<int SPLIT>
__global__ __launch_bounds__(256) void attn_mfma(
    const u16* __restrict__ qkv, const u16* __restrict__ vt,
    const float* __restrict__ sz, float* __restrict__ opart,
    float* __restrict__ lpart)
{
  const int h   = blockIdx.y;
  const int q0  = blockIdx.x * 64;
  const int tid = threadIdx.x;
  const int lane = tid & 63;
  const int w    = tid >> 6;
  const int col  = lane & 15;
  const int quad = lane >> 4;

  __shared__ u16 Ks [64 * 64] __attribute__((aligned(16)));  // [key][d] swizzled
  __shared__ u16 Vts[64 * 64] __attribute__((aligned(16)));  // [d][key] swizzled
  __shared__ u16 Ps[4][16 * 72] __attribute__((aligned(16)));// per-wave P[q][key] bf16
  __shared__ float lb[64];

  bf16x8 qf[2];
  {
    const u16* qp = qkv + (size_t)(q0 + w * 16 + col) * 3072 + h * 64 + quad * 8;
    qf[0] = *(const bf16x8*)(qp);
    qf[1] = *(const bf16x8*)(qp + 32);
  }

  float l_lane = 0.f;          // all partials belong to q = q0 + w*16 + col
  f32x4 oacc[4] = {};

  const int rl = lane >> 3;
  const int cg = (lane & 7) ^ rl;
  const int kb = blockIdx.z * (N_TOK / SPLIT);

  for (int kt = kb; kt < kb + N_TOK / SPLIT; kt += 64) {
    #pragma unroll
    for (int i = 0; i < 2; i++) {
      const int r = w * 16 + i * 8 + rl;
      __builtin_amdgcn_global_load_lds(
          (const __attribute__((address_space(1))) void*)(qkv + (size_t)(kt + r) * 3072 + 1024 + h * 64 + cg * 8),
          (__attribute__((address_space(3))) void*)(Ks + (w * 16 + i * 8) * 64),
          16, 0, 0);
      __builtin_amdgcn_global_load_lds(
          (const __attribute__((address_space(1))) void*)(vt + (size_t)(h * 64 + r) * 2048 + kt + cg * 8),
          (__attribute__((address_space(3))) void*)(Vts + (w * 16 + i * 8) * 64),
          16, 0, 0);
    }
    if (tid < 64) lb[tid] = __logf(sz[kt + tid]);
    __syncthreads();

    // S^T = K Q^T : lane holds S^T[key = jt*16+quad*4+r][q = col]
    f32x4 sacc[4] = {};
    #pragma unroll
    for (int kk = 0; kk < 2; kk++) {
      const int slot = (kk * 4 + quad) ^ (lane & 7);
      #pragma unroll
      for (int jt = 0; jt < 4; jt++) {
        bf16x8 kf = *(const bf16x8*)&Ks[(jt * 16 + col) * 64 + slot * 8];
        sacc[jt] = __builtin_amdgcn_mfma_f32_16x16x32_bf16(kf, qf[kk], sacc[jt], 0, 0, 0);
      }
    }

    // exp + packed P-writes (4x b64), l accumulates per-lane
    u16* pw = Ps[w];
    #pragma unroll
    for (int jt = 0; jt < 4; jt++) {
      float4 lb4 = *(const float4*)&lb[jt * 16 + quad * 4];
      const float p0 = __expf(fmaf(sacc[jt][0], 0.125f, lb4.x));
      const float p1 = __expf(fmaf(sacc[jt][1], 0.125f, lb4.y));
      const float p2 = __expf(fmaf(sacc[jt][2], 0.125f, lb4.z));
      const float p3 = __expf(fmaf(sacc[jt][3], 0.125f, lb4.w));
      l_lane += (p0 + p1) + (p2 + p3);
      ushort4 pk;
      pk.x = f2bf(p0); pk.y = f2bf(p1); pk.z = f2bf(p2); pk.w = f2bf(p3);
      *(ushort4*)&pw[col * 72 + jt * 16 + quad * 4] = pk;
    }
    // same-wave LDS RAW -> lgkmcnt (verified pattern); rows 144B apart
    bf16x8 pf[2];
    #pragma unroll
    for (int kk = 0; kk < 2; kk++)
      pf[kk] = *(const bf16x8*)&pw[col * 72 + kk * 32 + quad * 8];

    // O += P V (A = P rows=q, B = V^T)
    #pragma unroll
    for (int kk = 0; kk < 2; kk++) {
      const int slot = (kk * 4 + quad) ^ (lane & 7);
      #pragma unroll
      for (int nt = 0; nt < 4; nt++) {
        bf16x8 vf = *(const bf16x8*)&Vts[(nt * 16 + col) * 64 + slot * 8];
        oacc[nt] = __builtin_amdgcn_mfma_f32_16x16x32_bf16(pf[kk], vf, oacc[nt], 0, 0, 0);
      }
    }
    __syncthreads();
  }

  // l: sum the 4 quads of each col group (once)
  l_lane += __shfl_xor(l_lane, 16);
  l_lane += __shfl_xor(l_lane, 32);

  #pragma unroll
  for (int r = 0; r < 4; r++) {
    const int q = q0 + w * 16 + quad * 4 + r;
    float* op = opart + (size_t)q * 1024 + h * 64 + col;
    #pragma unroll
    for (int nt = 0; nt < 4; nt++)
      atomicAdd(op + nt * 16, oacc[nt][r]);
  }
  if (quad == 0)
    atomicAdd(&lpart[(q0 + w * 16 + col) * 16 + h], l_lane);
}

// ---------------- normalize O by l, emit bf16 xa --------------------------
__global__ __launch_bounds__(256) void attn_norm_kernel(
    const float* __restrict__ opart, const float* __restrict__ lpart,
    u16* __restrict__ xa)
{
  const int q = blockIdx.x;
  const int c = threadIdx.x * 4;
  float4 o = *(const float4*)(opart + (size_t)q * 1024 + c);
  const float inv = 1.0f / lpart[q * 16 + (c >> 6)];
  ushort4 o4;
  o4.x = f2bf(o.x * inv); o4.y = f2bf(o.y * inv);
  o4.z = f2bf(o.z * inv); o4.w = f2bf(o.w * inv);
  *(ushort4*)(xa + (size_t)q * 1024 + c) = o4;
}

// ---------------- merge scores: 4 src/block, identical comparator ---------
__global__ __launch_bounds__(256) void merge_score_kernel(
    const float* __restrict__ metric, const float* __restrict__ thr,
    int* __restrict__ mask, int* __restrict__ node)
{
  const int s0 = blockIdx.x * 4;
  const int t = threadIdx.x;
  __shared__ float a[4][64];
  a[t >> 6][t & 63] = metric[(size_t)(2 * (s0 + (t >> 6))) * 64 + (t & 63)];
  __syncthreads();
  float best[4] = {-INFINITY, -INFINITY, -INFINITY, -INFINITY};
  int besti[4] = {0, 0, 0, 0};
  for (int m = t; m < 1024; m += 256) {
    const float* bp = metric + (size_t)(2 * m + 1) * 64;
    float s[4] = {0.f, 0.f, 0.f, 0.f};
    #pragma unroll
    for (int d = 0; d < 64; d += 4) {
      float4 bv = *(const float4*)(bp + d);
      #pragma unroll
      for (int j = 0; j < 4; j++) {
        float4 av = *(const float4*)&a[j][d];
        s[j] += av.x*bv.x + av.y*bv.y + av.z*bv.z + av.w*bv.w;
      }
    }
    #pragma unroll
    for (int j = 0; j < 4; j++)
      if (s[j] > best[j]) { best[j] = s[j]; besti[j] = m; }   // ascending m
  }
  #pragma unroll
  for (int j = 0; j < 4; j++) {
    float b = best[j]; int bi = besti[j];
    #pragma unroll
    for (int off = 1; off < 64; off <<= 1) {
      float ov = __shfl_xor(b, off);
      int   oi = __shfl_xor(bi, off);
      if (ov > b || (ov == b && oi < bi)) { b = ov; bi = oi; }
    }
    best[j] = b; besti[j] = bi;
  }
  __shared__ float bw_[4][4]; __shared__ int biw_[4][4];
  const int wv = t >> 6;
  if ((t & 63) == 0) {
    #pragma unroll
    for (int j = 0; j < 4; j++) { bw_[wv][j] = best[j]; biw_[wv][j] = besti[j]; }
  }
  __syncthreads();
  if (t < 4) {
    const int j = t;
    float b = bw_[0][j]; int bi = biw_[0][j];
    for (int ww = 1; ww < 4; ww++)
      if (bw_[ww][j] > b || (bw_[ww][j] == b && biw_[ww][j] < bi)) { b = bw_[ww][j]; bi = biw_[ww][j]; }
    const int n = s0 + j;
    if (n == 0) { mask[0] = 0; node[0] = 0; }
    else { mask[n] = (b > thr[0]) ? 1 : 0; node[n] = bi; }
  }
}

// ---------------- exclusive prefix-sum of !mask (1024 entries) ------------
__global__ __launch_bounds__(1024) void scan_kernel(
    const int* __restrict__ mask, int* __restrict__ pos)
{
  __shared__ int s[1024];
  const int t = threadIdx.x;
  const int v0 = mask[t] ? 0 : 1;
  s[t] = v0;
  __syncthreads();
  for (int off = 1; off < 1024; off <<= 1) {
    int v = (t >= off) ? s[t - off] : 0;
    __syncthreads();
    s[t] += v;
    __syncthreads();
  }
  pos[t] = s[t] - v0;
}

// ---------------- build merged rows (unm gather + dst base) ---------------
__global__ __launch_bounds__(256) void build_kernel(
    const float* __restrict__ xres, const float* __restrict__ sz,
    const int* __restrict__ mask, const int* __restrict__ pos,
    float* __restrict__ xm, float* __restrict__ sizem, int U)
{
  const int b = blockIdx.x;
  const int t = threadIdx.x;
  int srow, orow;
  if (b < 1024) { srow = 2 * b + 1; orow = U + b; }
  else {
    const int i = b - 1024;
    if (mask[i]) return;
    srow = 2 * i; orow = pos[i];
  }
  const float ssz = sz[srow];
  const float* xp = xres + (size_t)srow * 1024;
  float* op = xm + (size_t)orow * 1024;
  const int c = t * 4;
  float4 v = *(const float4*)(xp + c);
  v.x *= ssz; v.y *= ssz; v.z *= ssz; v.w *= ssz;
  *(float4*)(op + c) = v;
  if (t == 0) sizem[orow] = ssz;
}

// ---------------- scatter-add merged src tokens into dst rows -------------
__global__ __launch_bounds__(256) void merge_add_kernel(
    const float* __restrict__ xres, const float* __restrict__ sz,
    const int* __restrict__ mask, const int* __restrict__ node,
    float* __restrict__ xm, float* __restrict__ sizem, int U)
{
  const int i = blockIdx.x;
  if (!mask[i]) return;
  const int t = threadIdx.x;
  const int srow = 2 * i;
  const int orow = U + node[i];
  const float ssz = sz[srow];
  const float* xp = xres + (size_t)srow * 1024;
  float* op = xm + (size_t)orow * 1024;
  for (int c = t; c < 1024; c += 256)
    atomicAdd(op + c, xp[c] * ssz);
  if (t == 0) atomicAdd(sizem + orow, ssz);
}

// ---------------- divide by size; emit x and size outputs -----------------
__global__ __launch_bounds__(256) void divide_kernel(
    const float* __restrict__ xm, const float* __restrict__ sizem,
    float* __restrict__ outx, float* __restrict__ outs, int M)
{
  const int total = M * 1024;
  for (int idx = blockIdx.x * 256 + threadIdx.x; idx < total; idx += gridDim.x * 256)
    outx[idx] = xm[idx] / sizem[idx >> 10];
  const int idx2 = blockIdx.x * 256 + threadIdx.x;
  if (idx2 < M) outs[idx2] = sizem[idx2];
}

extern "C" void kernel_launch(void* const* d_in, const int* in_sizes, int n_in,
                              void* d_out, int out_size, void* d_ws, size_t ws_size,
                              hipStream_t stream) {
  const float* x      = (const float*)d_in[0];
  const float* sz     = (const float*)d_in[1];
  const float* qkv_w  = (const float*)d_in[2];
  const float* proj_w = (const float*)d_in[3];
  const float* proj_b = (const float*)d_in[4];
  const float* ln1_g  = (const float*)d_in[5];
  const float* ln1_b  = (const float*)d_in[6];
  const float* ln2_g  = (const float*)d_in[7];
  const float* ln2_b  = (const float*)d_in[8];
  const float* fc1_w  = (const float*)d_in[9];
  const float* fc1_b  = (const float*)d_in[10];
  const float* fc2_w  = (const float*)d_in[11];
  const float* fc2_b  = (const float*)d_in[12];
  const float* thr    = (const float*)d_in[13];

  const int M = out_size / 1025;
  const int U = M - 1024;
  const size_t MB = 1u << 20;
  const size_t KB = 1u << 10;

  // workspace overlays (lifetimes sequential on `stream`):
  //  early: w_qkvT[0,6) -> b_vt[0,4); wbar/met/mask@[6,7); lpart@[7,7.13);
  //         w_projT[8,10); b_qkv[10,22) -> b_xm[10,18);
  //         b_hf[22,30) -> opart[22,30) -> b_xres[22,30);
  //         b_h[30,34) -> b_xa[30,34)
  //  late:  w_fc1T[0,8); b_g[8,21); w_fc2T[21,29); facc[29,35); b_h2[35,39)
  char* ws = (char*)d_ws;
  u16*   w_qkvT  = (u16*)(ws + 0);
  float* b_wbar  = (float*)(ws + 6 * MB);
  float* b_met   = (float*)(ws + 6 * MB + 256 * KB);
  int*   b_mask  = (int*)(ws + 6 * MB + 768 * KB);
  int*   b_node  = b_mask + 1024;
  int*   b_pos   = b_node + 1024;
  float* b_szm   = (float*)(b_pos + 1024);
  float* b_lpart = (float*)(ws + 7 * MB);
  u16*   w_projT = (u16*)(ws + 8 * MB);
  u16*   b_qkv   = (u16*)(ws + 10 * MB);
  float* b_xm    = (float*)(ws + 10 * MB);   // over dead b_qkv
  float* b_hf    = (float*)(ws + 22 * MB);
  float* b_opart = (float*)(ws + 22 * MB);   // over dead b_hf
  float* b_xres  = (float*)(ws + 22 * MB);   // over dead opart
  u16*   b_h     = (u16*)(ws + 30 * MB);
  u16*   b_xa    = (u16*)(ws + 30 * MB);
  u16*   b_vt    = (u16*)(ws + 0);
  u16*   w_fc1T  = (u16*)(ws + 0);
  u16*   b_g     = (u16*)(ws + 8 * MB);
  u16*   w_fc2T  = (u16*)(ws + 21 * MB);
  float* b_facc  = (float*)(ws + 29 * MB);
  u16*   b_h2    = (u16*)(ws + 35 * MB);

  float* outx = (float*)d_out;
  float* outs = outx + (size_t)M * 1024;

  // 1. LN1 -> bf16 (for MFMA) + fp32 (for exact metric path)
  ln_kernel<<<2048, 256, 0, stream>>>(x, ln1_g, ln1_b, b_h, b_hf);
  // 2. mean-over-heads k-weights (fp32)
  wbar_kernel<<<256, 256, 0, stream>>>(qkv_w, b_wbar);
  // 3. weight converts for attention half
  convert_transpose<<<dim3(96, 32), 256, 0, stream>>>(qkv_w, w_qkvT, 1024, 3072);
  convert_transpose<<<dim3(32, 32), 256, 0, stream>>>(proj_w, w_projT, 1024, 1024);
  // 4. QKV GEMM (bf16 MFMA), bf16 out — 768 blocks
  gemm_mfma<128, 1, false, false, false, true><<<dim3(48, 16), 256, 0, stream>>>(
      b_h, w_qkvT, nullptr, nullptr, b_qkv, 2048, 3072, 1024);
  // 4b. V transpose for MFMA attention (overwrites dead w_qkvT)
  vt_kernel<<<dim3(32, 16), 256, 0, stream>>>(b_qkv, b_vt);
  // 5. exact fp32 metric (decoupled from bf16 path — merge decisions stable)
  metric_gemm_kernel<<<512, 256, 0, stream>>>(b_hf, b_wbar, b_met);
  // 6. MFMA attention (R6 shape, S^T trick), key-split=2, atomic partials
  hipMemsetAsync(b_opart, 0, 8 * MB, stream);
  hipMemsetAsync(b_lpart, 0, 128 * KB, stream);
  attn_mfma<2><<<dim3(32, 16, 2), 256, 0, stream>>>(b_qkv, b_vt, sz, b_opart, b_lpart);
  attn_norm_kernel<<<2048, 256, 0, stream>>>(b_opart, b_lpart, b_xa);
  // 7. proj GEMM + bias + residual(x) -> xres fp32 — 512 blocks
  gemm_mfma<64, 1, true, false, true, false><<<dim3(16, 32), 256, 0, stream>>>(
      b_xa, w_projT, proj_b, x, b_xres, 2048, 1024, 1024);
  // 8-11. merge pipeline
  merge_score_kernel<<<256, 256, 0, stream>>>(b_met, thr, b_mask, b_node);
  scan_kernel<<<1, 1024, 0, stream>>>(b_mask, b_pos);
  build_kernel<<<2048, 256, 0, stream>>>(b_xres, sz, b_mask, b_pos, b_xm, b_szm, U);
  merge_add_kernel<<<1024, 256, 0, stream>>>(b_xres, sz, b_mask, b_node, b_xm, b_szm, U);
  // 12. divide + emit outputs
  divide_kernel<<<2048, 256, 0, stream>>>(b_xm, b_szm, outx, outs, M);
  // 13. late weight converts (into now-dead regions)
  convert_transpose<<<dim3(128, 32), 256, 0, stream>>>(fc1_w, w_fc1T, 1024, 4096);
  convert_transpose<<<dim3(32, 128), 256, 0, stream>>>(fc2_w, w_fc2T, 4096, 1024);
  // 14. LN2 -> bf16
  ln_kernel<<<M, 256, 0, stream>>>(outx, ln2_g, ln2_b, b_h2, nullptr);
  // 15. fc1 + bias + exact GELU -> bf16 — 768 blocks
  gemm_mfma<128, 1, true, true, false, true><<<dim3(64, (M + 127) / 128), 256, 0, stream>>>(
      b_h2, w_fc1T, fc1_b, nullptr, b_g, M, 4096, 1024);
  // 16. fc2 split-K=4 -> fp32 atomic accumulator
  hipMemsetAsync(b_facc, 0, (size_t)M * 1024 * 4, stream);
  gemm_mfma<64, 4, false, false, false, false><<<dim3(16, (M + 63) / 64, 4), 256, 0, stream>>>(
      b_g, w_fc2T, nullptr, nullptr, b_facc, M, 1024, 4096);
  // 17. fc2 epilogue: outx += facc + bias (residual in-place)
  splitk_epilogue_kernel<<<(M * 256 + 255) / 256, 256, 0, stream>>>(
      b_facc, fc2_b, outx, M);
  (void)in_sizes; (void)n_in; (void)ws_size;
}